// Round 4
// baseline (238.879 us; speedup 1.0000x reference)
//
#include <hip/hip_runtime.h>

// Bilinear resampling: feature_map [C,H,W] fp32, target_uv [N,2] fp32, downscale (int scalar)
// out [C,N] fp32.
constexpr int C = 128, H = 376, W = 1248;
constexpr int HW = H * W;
constexpr int CPG = 2;          // channels per group (per-XCD L2 working set = CPG*1.88MB < 4MB)
constexpr int CG  = C / CPG;    // 64 channel groups
constexpr int NXCD = 8;
constexpr int GPX  = CG / NXCD; // 8 channel groups owned per XCD

typedef float vfloat2 __attribute__((ext_vector_type(2)));   // native vector: OK for nontemporal builtin

__global__ __launch_bounds__(256) void BilinearResampling_kernel(
    const float* __restrict__ fmap,
    const float* __restrict__ uv,
    const int*   __restrict__ dsp,
    float*       __restrict__ out,
    int N, int NBX)
{
    // XCD-exclusive channel-group ownership (bid % 8 == XCD round-robin):
    // each XCD owns a contiguous slice of channel groups; within an XCD,
    // groups run sequentially (group-major) so one 3.75MB plane-pair is the
    // L2 working set at a time.
    int bid = blockIdx.x;
    int xcd = bid & 7;
    int j   = bid >> 3;
    int g_local = j / NBX;
    int nb      = j - g_local * NBX;
    int g   = xcd * GPX + g_local;

    int i  = nb * 256 + threadIdx.x;   // point-pair index
    int n0 = i * 2;
    if (n0 >= N) return;
    bool has1 = (n0 + 1) < N;

    float dsf = (float)dsp[0];

    // Two points per thread: one aligned 16B uv load.
    float4 pq = ((const float4*)uv)[i];

    float u0 = pq.x / dsf, v0 = pq.y / dsf;
    float u1 = pq.z / dsf, v1 = pq.w / dsf;

    int u0l = (int)u0, v0l = (int)v0;
    int u1l = (int)u1, v1l = (int)v1;
    float du0 = u0 - (float)u0l, dv0 = v0 - (float)v0l;
    float du1 = u1 - (float)u1l, dv1 = v1 - (float)v1l;

    float a00 = (1.0f - dv0) * (1.0f - du0);
    float a10 = dv0 * (1.0f - du0);
    float a01 = (1.0f - dv0) * du0;
    float a11 = dv0 * du0;

    float b00 = (1.0f - dv1) * (1.0f - du1);
    float b10 = dv1 * (1.0f - du1);
    float b01 = (1.0f - dv1) * du1;
    float b11 = dv1 * du1;

    int cbase = g * CPG;
    const float* fpA = fmap + (size_t)cbase * HW + (size_t)v0l * W + u0l;
    const float* fpB = fmap + (size_t)cbase * HW + (size_t)v1l * W + u1l;
    float*       op  = out  + (size_t)cbase * N + n0;

#pragma unroll
    for (int c = 0; c < CPG; ++c) {
        // Paired gathers: (f00,f01) and (f10,f11) are adjacent -> one dwordx2 each.
        float2 aLo = *(const float2*)(fpA);
        float2 aHi = *(const float2*)(fpA + W);
        float2 bLo = *(const float2*)(fpB);
        float2 bHi = *(const float2*)(fpB + W);

        float r0 = aLo.x * a00 + aHi.x * a10 + aLo.y * a01 + aHi.y * a11;
        float r1 = bLo.x * b00 + bHi.x * b10 + bLo.y * b01 + bHi.y * b11;

        if (has1) {
            vfloat2 rr = {r0, r1};
            __builtin_nontemporal_store(rr, (vfloat2*)op);  // coalesced 8B store
        } else {
            __builtin_nontemporal_store(r0, op);
        }
        fpA += HW;
        fpB += HW;
        op  += N;
    }
}

extern "C" void kernel_launch(void* const* d_in, const int* in_sizes, int n_in,
                              void* d_out, int out_size, void* d_ws, size_t ws_size,
                              hipStream_t stream)
{
    const float* fmap = (const float*)d_in[0];
    const float* uv   = (const float*)d_in[1];
    const int*   dsp  = (const int*)d_in[2];
    float*       out  = (float*)d_out;

    int N  = in_sizes[1] / 2;            // target_uv has N*2 elements
    int NP = (N + 1) / 2;                // point pairs
    int NBX = (NP + 255) / 256;          // blocks along the pair dimension

    dim3 grid(NBX * CG);
    dim3 block(256);
    BilinearResampling_kernel<<<grid, block, 0, stream>>>(fmap, uv, dsp, out, N, NBX);
}